// Round 2
// baseline (178.508 us; speedup 1.0000x reference)
//
#include <hip/hip_runtime.h>

// TrajectoryScore: truncated-exponential mixture scoring + segment sums.
// 64 segments x 100,000 obs, fp32. 153.6 MB input stream -> ~24 us HBM floor
// (less if LLC-resident). v2: unit-stride float3 loads (12B lane stride,
// every cache line fully consumed per instruction) + 12-obs full unroll for
// deep memory-level parallelism per wave.

constexpr int ELT_BATCH      = 64;
constexpr int OBS_PER_ELT    = 100000;
constexpr int BLOCK          = 256;
constexpr int BLOCKS_PER_SEG = 32;
constexpr int TPS            = BLOCK * BLOCKS_PER_SEG;        // 8192 threads/segment
constexpr int FULL_ITERS     = OBS_PER_ELT / TPS;             // 12
constexpr int TAIL           = OBS_PER_ELT - FULL_ITERS * TPS; // 1696

struct F3 { float x, y, z; };   // 12 B, loads as global_load_dwordx3

__device__ __forceinline__ void process_obs(
    const F3 a, const F3 b,
    const float th, const float nli, const float coef, const float omh,
    float& ll, float& hs)
{
    const float dx = a.x - b.x;
    const float dy = a.y - b.y;
    const float dz = a.z - b.z;
    const float s2 = dx * dx + dy * dy + dz * dz;
    const float e     = __expf(nli * s2);      // exp(-lam * s2 / th)
    const float p_hit = coef * e;
    const float p     = p_hit + omh;
    const bool  close = s2 < th;
    const float lp    = __logf(p);
    ll += close ? lp : 0.0f;
    const float post  = p_hit / p;
    hs += (close && post > 0.95f) ? post : 0.0f;
}

__device__ __forceinline__ float wave_reduce_sum(float v) {
    #pragma unroll
    for (int off = 32; off > 0; off >>= 1)
        v += __shfl_down(v, off, 64);
    return v;
}

__global__ __launch_bounds__(BLOCK) void TrajectoryScore_58145267253396_kernel(
    const F3*    __restrict__ pred,
    const F3*    __restrict__ obs,
    const float* __restrict__ h_arr,
    const float* __restrict__ lam_arr,
    const float* __restrict__ th_arr,
    float*       __restrict__ out)
{
    const int seg = blockIdx.x / BLOCKS_PER_SEG;
    const int g   = (blockIdx.x % BLOCKS_PER_SEG) * BLOCK + threadIdx.x;

    // Wave-uniform per-segment params.
    const float h    = h_arr[seg];
    const float lam  = lam_arr[seg];
    const float th   = th_arr[seg];
    const float coef = h * lam / (1.0f - __expf(-lam));
    const float omh  = 1.0f - h;
    const float nli  = -lam / th;

    float ll = 0.0f;
    float hs = 0.0f;

    const int base = seg * OBS_PER_ELT + g;

    // 12 obs per thread, batches of 6: 12 loads issued back-to-back before
    // the dependent compute -> deep MLP, all loads unit-stride across lanes.
    #pragma unroll
    for (int half = 0; half < 2; ++half) {
        F3 a[6], b[6];
        #pragma unroll
        for (int j = 0; j < 6; ++j) {
            const int idx = base + (half * 6 + j) * TPS;
            a[j] = pred[idx];
            b[j] = obs[idx];
        }
        #pragma unroll
        for (int j = 0; j < 6; ++j)
            process_obs(a[j], b[j], th, nli, coef, omh, ll, hs);
    }

    // Ragged tail: first TAIL threads of the segment take one extra obs.
    if (g < TAIL) {
        const int idx = base + FULL_ITERS * TPS;
        process_obs(pred[idx], obs[idx], th, nli, coef, omh, ll, hs);
    }

    // Block reduction: 64-lane shuffle, then LDS across the 4 waves.
    ll = wave_reduce_sum(ll);
    hs = wave_reduce_sum(hs);

    __shared__ float sll[BLOCK / 64];
    __shared__ float shs[BLOCK / 64];
    const int wave = threadIdx.x >> 6;
    const int lane = threadIdx.x & 63;
    if (lane == 0) { sll[wave] = ll; shs[wave] = hs; }
    __syncthreads();
    if (threadIdx.x == 0) {
        float L = 0.0f, H = 0.0f;
        #pragma unroll
        for (int w = 0; w < BLOCK / 64; ++w) { L += sll[w]; H += shs[w]; }
        atomicAdd(&out[seg], L);
        atomicAdd(&out[ELT_BATCH + seg], H);
        atomicAdd(&out[2 * ELT_BATCH + seg], H);  // hits_raw == hits
    }
}

extern "C" void kernel_launch(void* const* d_in, const int* in_sizes, int n_in,
                              void* d_out, int out_size, void* d_ws, size_t ws_size,
                              hipStream_t stream) {
    const F3*    pred    = (const F3*)d_in[0];
    const F3*    obs     = (const F3*)d_in[1];
    const float* h_arr   = (const float*)d_in[2];
    const float* lam_arr = (const float*)d_in[3];
    const float* th_arr  = (const float*)d_in[4];
    float* out = (float*)d_out;

    // Harness poisons d_out to 0xAA before timed replays — zero it ourselves.
    hipMemsetAsync(out, 0, out_size * sizeof(float), stream);

    dim3 grid(ELT_BATCH * BLOCKS_PER_SEG);
    dim3 block(BLOCK);
    TrajectoryScore_58145267253396_kernel<<<grid, block, 0, stream>>>(
        pred, obs, h_arr, lam_arr, th_arr, out);
}